// Round 8
// baseline (886.249 us; speedup 1.0000x reference)
//
#include <hip/hip_runtime.h>

// Problem constants
#define N_ROWS 131072    // 32*4096
#define D 64
#define K_CODES 1024

typedef _Float16 f16x8  __attribute__((ext_vector_type(8)));
typedef float    f32x16 __attribute__((ext_vector_type(16)));

#define MFMA32(a, b, c) __builtin_amdgcn_mfma_f32_32x32x16_f16((a), (b), (c), 0, 0, 0)

// ---------------------------------------------------------------------------
// ws layout: csqr[1024] f32 (4 KB) | CBf: 16384 f16x8 units (256 KB)
// 32x32x16 B-fragment order: unit = tile*512 + (ks*2+p)*64 + lane
//   tile 0..31 (32 codes each), ks 0..3 (k = ks*16..+15), p 0:hi 1:lo,
//   unit holds B[k = ks*16 + (lane>>5)*8 + j][n = lane&31], code = tile*32+n.
// => argmin B loads are 8 coalesced 16B reads per 32-code tile.
// ---------------------------------------------------------------------------
__global__ __launch_bounds__(256)
void prep_kernel(const float* __restrict__ CB, _Float16* __restrict__ CBf,
                 float* __restrict__ csqr, float* __restrict__ loss) {
    const int b = blockIdx.x, t = threadIdx.x;
    if (b < 64) {
        const int u    = b * 256 + t;        // unit 0..16383
        const int tile = u >> 9;
        const int ks   = (u >> 7) & 3;
        const int p    = (u >> 6) & 1;
        const int lane = u & 63;
        const int code = tile * 32 + (lane & 31);
        const int k0   = ks * 16 + (lane >> 5) * 8;
        const float* src = CB + (size_t)code * D + k0;
        float4 v0 = *(const float4*)(src);
        float4 v1 = *(const float4*)(src + 4);
        float xs[8] = {v0.x, v0.y, v0.z, v0.w, v1.x, v1.y, v1.z, v1.w};
        f16x8 o;
#pragma unroll
        for (int j = 0; j < 8; ++j) {
            _Float16 h = (_Float16)xs[j];
            o[j] = (p == 0) ? h : (_Float16)(xs[j] - (float)h);
        }
        *(f16x8*)(CBf + (size_t)u * 8) = o;
    } else {
        if (t == 0) *loss = 0.0f;
        for (int k = t; k < K_CODES; k += 256) {
            const float4* p4 = (const float4*)(CB + (size_t)k * D);
            float s = 0.0f;
#pragma unroll
            for (int i = 0; i < 16; ++i) {
                float4 v = p4[i];
                s += v.x * v.x + v.y * v.y + v.z * v.z + v.w * v.w;
            }
            csqr[k] = s;
        }
    }
}

// ---------------------------------------------------------------------------
// K1: 32x32x16 split-f16 MFMA argmin + fused z_q + loss.
// Block = 64 rows, 4 waves = (row-half, code-half):
//   wave w: rows [R0+(w>>1)*32, +32) x codes [(w&1)*512, +512) = 16 tiles
//   of 32 codes; ONE 32x32 MFMA covers the wave's whole row set per tile.
// A = (-2x) hi/lo in regs (32 VGPR). B double-buffered from fragment-ordered
// CBf (L2-resident). Per tile: 12-MFMA chain (hh x4 ks, lh x4, hl x4;
// ll ~2^-24 dropped) = 17% fewer matrix-pipe cycles than the 16x16x32 form,
// half the instruction count. score = |c|^2 + (-2x)·c, acc-init = csqr.
// D layout (32x32): col = lane&31 (code), row = (r&3) + 8*(r>>2) + 4*(lane>>5).
// Cross-wave merge via LDS (code-half 0 has smaller indices). Epilogue:
// block-cooperative contiguous zq span write (16B-aligned despite out+1).
// ---------------------------------------------------------------------------
__global__ __launch_bounds__(256, 3)
void argmin_kernel(const float* __restrict__ X,
                   const _Float16* __restrict__ CBf,
                   const float* __restrict__ csqr,
                   const float* __restrict__ CB,
                   float* __restrict__ out) {
    __shared__ float LsC[K_CODES];       // csqr copy, 4 KB
    __shared__ float candD[64][2];
    __shared__ int   candI[64][2];
    __shared__ int   ivfin[64];
    __shared__ float xsqW[2];

    const int t    = threadIdx.x;
    const int wave = t >> 6;
    const int lane = t & 63;
    const int col  = lane & 31;          // A row-in-tile / B+D column (code)
    const int half = lane >> 5;          // k-half selector
    const int rh   = wave >> 1;          // row half
    const int ch   = wave & 1;           // code half
    const int R0   = blockIdx.x * 64;
    const int Rw   = R0 + rh * 32;

    // Stage csqr to LDS (covered by the barrier below).
    ((float4*)LsC)[t] = ((const float4*)csqr)[t];

    // ---- A fragments: (-2x) split hi/lo. 32x32x16 A layout: lane holds
    // A[m = lane&31][k = ks*16 + (lane>>5)*8 + j], j=0..7.
    // Wave covers each of its 32 rows' 64 elements exactly once -> xsq.
    f16x8 Ah[4], Al[4];
    float xsq = 0.0f;
    {
        const float* xr = X + (size_t)(Rw + col) * D;
#pragma unroll
        for (int ks = 0; ks < 4; ++ks) {
            const int k0 = ks * 16 + half * 8;
            float4 v0 = *(const float4*)(xr + k0);
            float4 v1 = *(const float4*)(xr + k0 + 4);
            float xs[8] = {v0.x, v0.y, v0.z, v0.w, v1.x, v1.y, v1.z, v1.w};
            f16x8 h, l;
#pragma unroll
            for (int j = 0; j < 8; ++j) {
                xsq += xs[j] * xs[j];
                float sv = -2.0f * xs[j];
                _Float16 hh = (_Float16)sv;
                h[j] = hh;
                l[j] = (_Float16)(sv - (float)hh);
            }
            Ah[ks] = h;
            Al[ks] = l;
        }
    }
    __syncthreads();   // LsC ready

    float bestd[16];
    int   besti[16];
#pragma unroll
    for (int r = 0; r < 16; ++r) { bestd[r] = 3.0e38f; besti[r] = 0; }

    // Wave's code half starts at tile ch*16. Units per tile = 512.
    const f16x8* gw = (const f16x8*)CBf + (size_t)ch * 16 * 512 + lane;

// Bv[2k] = hi(ks=k), Bv[2k+1] = lo(ks=k)
#define LOADB(Bv, tl)                                                         \
    do {                                                                      \
        const f16x8* _p = gw + (size_t)(tl) * 512;                            \
        Bv[0] = _p[0];   Bv[1] = _p[64];  Bv[2] = _p[128]; Bv[3] = _p[192];   \
        Bv[4] = _p[256]; Bv[5] = _p[320]; Bv[6] = _p[384]; Bv[7] = _p[448];   \
    } while (0)

#define COMPUTE(Bv, tl)                                                       \
    do {                                                                      \
        const int   c  = ((ch * 16 + (tl)) << 5) + col;                       \
        const float cs = LsC[c];                                              \
        f32x16 acc;                                                           \
        _Pragma("unroll")                                                     \
        for (int r = 0; r < 16; ++r) acc[r] = cs;                             \
        acc = MFMA32(Ah[0], Bv[0], acc);                                      \
        acc = MFMA32(Ah[1], Bv[2], acc);                                      \
        acc = MFMA32(Ah[2], Bv[4], acc);                                      \
        acc = MFMA32(Ah[3], Bv[6], acc);                                      \
        acc = MFMA32(Al[0], Bv[0], acc);                                      \
        acc = MFMA32(Al[1], Bv[2], acc);                                      \
        acc = MFMA32(Al[2], Bv[4], acc);                                      \
        acc = MFMA32(Al[3], Bv[6], acc);                                      \
        acc = MFMA32(Ah[0], Bv[1], acc);                                      \
        acc = MFMA32(Ah[1], Bv[3], acc);                                      \
        acc = MFMA32(Ah[2], Bv[5], acc);                                      \
        acc = MFMA32(Ah[3], Bv[7], acc);                                      \
        _Pragma("unroll")                                                     \
        for (int r = 0; r < 16; ++r) {                                        \
            bool lt = acc[r] < bestd[r];                                      \
            bestd[r] = lt ? acc[r] : bestd[r];                                \
            besti[r] = lt ? c : besti[r];                                     \
        }                                                                     \
    } while (0)

    // 16 local tiles, simple register double-buffer (R5's proven shape).
    // Overrun prefetches wrap via &15 (reloaded, never computed) so all
    // loads stay inside CBf. Codes ascend with tl for fixed lane ->
    // strict < keeps the first minimum (np.argmin semantics).
    f16x8 Ba[8], Bb[8];
    LOADB(Ba, 0);
    for (int tl = 0; tl < 16; tl += 2) {
        LOADB(Bb, (tl + 1) & 15);
        COMPUTE(Ba, tl);
        LOADB(Ba, (tl + 2) & 15);
        COMPUTE(Bb, tl + 1);
    }

    // ---- xsq: reduce within ch==0 waves (each block element once).
    if (ch == 0) {
        float s = xsq;
#pragma unroll
        for (int m = 1; m < 64; m <<= 1) s += __shfl_xor(s, m, 64);
        if (lane == 0) xsqW[rh] = s;
    }

    // ---- In-wave argmin reduce across the 32 code-columns (lexicographic
    // on exact ties), deposit per-row candidate for this code half.
    // D row for (r, half) = (r&3) + 8*(r>>2) + 4*half.
#pragma unroll
    for (int r = 0; r < 16; ++r) {
        float dv = bestd[r];
        int   iv = besti[r];
#pragma unroll
        for (int m = 1; m < 32; m <<= 1) {
            float od = __shfl_xor(dv, m, 64);
            int   oi = __shfl_xor(iv, m, 64);
            if (od < dv || (od == dv && oi < iv)) { dv = od; iv = oi; }
        }
        if (col == 0) {
            int rl = rh * 32 + (r & 3) + 8 * (r >> 2) + 4 * half;   // 0..63
            candD[rl][ch] = dv;
            candI[rl][ch] = iv;
        }
    }
    __syncthreads();

    // ---- Merge the two code halves; write idxf; accumulate loss.
    const float scale = 1.25f / (float)((size_t)N_ROWS * D);
    if (t < 64) {
        float d0 = candD[t][0], d1 = candD[t][1];
        int   i0 = candI[t][0], i1 = candI[t][1];
        // ch0 indices are all < ch1 indices -> tie keeps ch0 (first min).
        bool take1 = d1 < d0;
        float dv = take1 ? d1 : d0;
        int   iv = take1 ? i1 : i0;
        out[1 + (size_t)N_ROWS * D + R0 + t] = (float)iv;   // idxf
        ivfin[t] = iv;
        float ssum = dv;
#pragma unroll
        for (int m = 1; m < 64; m <<= 1) ssum += __shfl_xor(ssum, m, 64);
        if (t == 0)
            atomicAdd(out, (ssum + xsqW[0] + xsqW[1]) * scale);
    }
    __syncthreads();

    // ---- Block-cooperative zq span write: dwords [R0*64, R0*64+4096) at
    // out+1. Global dword offset 1+R0*64+j is 16B-aligned iff j%4==3.
    float* p = out + 1 + (size_t)R0 * D;
#pragma unroll
    for (int i = 0; i < 4; ++i) {
        int q = i * 256 + t;        // 0..1023
        int j = 4 * q + 3;          // 3,7,...,4095
        if (q < 1023) {
            float v[4];
#pragma unroll
            for (int e = 0; e < 4; ++e) {
                int jj = j + e;     // may straddle a row boundary
                v[e] = CB[(size_t)ivfin[jj >> 6] * D + (jj & 63)];
            }
            *(float4*)(p + j) = make_float4(v[0], v[1], v[2], v[3]);
        } else if (q == 1023) {
            p[4095] = CB[(size_t)ivfin[63] * D + 63];
        }
    }
    if (t == 0) {   // head dwords j=0..2 (row 0, cols 0..2)
        const float* c0 = CB + (size_t)ivfin[0] * D;
        p[0] = c0[0];
        p[1] = c0[1];
        p[2] = c0[2];
    }
}

// ---------------------------------------------------------------------------
extern "C" void kernel_launch(void* const* d_in, const int* in_sizes, int n_in,
                              void* d_out, int out_size, void* d_ws,
                              size_t ws_size, hipStream_t stream) {
    const float* X  = (const float*)d_in[0];   // inputs  [131072,64]
    const float* CB = (const float*)d_in[1];   // codebook [1024,64]

    float*    csqr = (float*)d_ws;                      // 4 KB
    _Float16* CBf  = (_Float16*)((char*)d_ws + 4096);   // 256 KB

    hipLaunchKernelGGL(prep_kernel, dim3(65), dim3(256), 0, stream,
                       CB, CBf, csqr, (float*)d_out);
    hipLaunchKernelGGL(argmin_kernel, dim3(N_ROWS / 64), dim3(256), 0, stream,
                       X, CBf, csqr, CB, (float*)d_out);
}

// Round 9
// 158.248 us; speedup vs baseline: 5.6004x; 5.6004x over previous
//
#include <hip/hip_runtime.h>

// Problem constants
#define N_ROWS 131072    // 32*4096
#define D 64
#define K_CODES 1024

typedef _Float16 f16x8 __attribute__((ext_vector_type(8)));
typedef float    f32x4 __attribute__((ext_vector_type(4)));

#define MFMA16(a, b, c) __builtin_amdgcn_mfma_f32_16x16x32_f16((a), (b), (c), 0, 0, 0)

// ---------------------------------------------------------------------------
// ws layout: csqr[1024] f32 (4 KB) | CBf: 16384 f16x8 units (256 KB)
// CBf unit index = tile*256 + f*64 + lane, f in {0:hi k0-31, 1:hi k32-63,
// 2:lo k0-31, 3:lo k32-63}; unit holds the 8 halves lane needs for that
// MFMA B fragment: B[k=(lane>>4)*8+j][n=lane&15], code = tile*16 + n.
// ---------------------------------------------------------------------------
__global__ __launch_bounds__(256)
void prep_kernel(const float* __restrict__ CB, _Float16* __restrict__ CBf,
                 float* __restrict__ csqr, float* __restrict__ loss) {
    const int b = blockIdx.x, t = threadIdx.x;
    if (b < 64) {
        const int unit = b * 256 + t;
        const int tile = unit >> 8;
        const int f    = (unit >> 6) & 3;
        const int lane = unit & 63;
        const int quad = lane >> 4, lrow = lane & 15;
        const int code = tile * 16 + lrow;
        const int k0   = (f & 1) * 32 + quad * 8;
        const float* src = CB + (size_t)code * D + k0;
        float4 v0 = *(const float4*)(src);
        float4 v1 = *(const float4*)(src + 4);
        float xs[8] = {v0.x, v0.y, v0.z, v0.w, v1.x, v1.y, v1.z, v1.w};
        f16x8 o;
#pragma unroll
        for (int j = 0; j < 8; ++j) {
            _Float16 h = (_Float16)xs[j];
            o[j] = (f < 2) ? h : (_Float16)(xs[j] - (float)h);
        }
        *(f16x8*)(CBf + (size_t)unit * 8) = o;
    } else {
        if (t == 0) *loss = 0.0f;
        for (int k = t; k < K_CODES; k += 256) {
            const float4* p = (const float4*)(CB + (size_t)k * D);
            float s = 0.0f;
#pragma unroll
            for (int i = 0; i < 16; ++i) {
                float4 v = p[i];
                s += v.x * v.x + v.y * v.y + v.z * v.z + v.w * v.w;
            }
            csqr[k] = s;
        }
    }
}

// ---------------------------------------------------------------------------
// K1: split-f16 MFMA argmin + fused z_q + loss, PINNED deep prefetch.
// Block = 64 rows, 4 waves partitioned as (row-half, code-half):
//   wave w: rows [R0 + (w>>1)*32, +32) x codes [(w&1)*512, +512)  (32 tiles).
// A = (-2x) hi/lo in regs (MT=2). B streamed from fragment-ordered CBf
// (L2-resident), 4-buffer / distance-3 register prefetch with
// __builtin_amdgcn_sched_barrier(0) after each load group so the scheduler
// CANNOT collapse the pipeline (R7 lesson: VGPR=80 proved it kept depth~1;
// stall model: ~450 cyc uncovered L2 latency per ~170 cyc issue tile).
// score = |c|^2 + (-2x)·c, acc-init = csqr, 6 MFMAs/tile/mt (hh,lh,hl;
// ll ~2^-24 dropped). Cross-wave merge via LDS (code-half 0 has smaller
// indices -> '<' keeps np.argmin first-min). Epilogue: block-cooperative
// contiguous zq span write (16B-aligned despite out+1).
// ---------------------------------------------------------------------------
__global__ __launch_bounds__(256, 3)
void argmin_kernel(const float* __restrict__ X,
                   const _Float16* __restrict__ CBf,
                   const float* __restrict__ csqr,
                   const float* __restrict__ CB,
                   float* __restrict__ out) {
    __shared__ float LsC[K_CODES];       // csqr copy, 4 KB
    __shared__ float candD[64][2];
    __shared__ int   candI[64][2];
    __shared__ int   ivfin[64];
    __shared__ float xsqW[2];

    const int t    = threadIdx.x;
    const int wave = t >> 6;
    const int lane = t & 63;
    const int lrow = lane & 15;
    const int quad = lane >> 4;
    const int rh   = wave >> 1;          // row half
    const int ch   = wave & 1;           // code half
    const int R0   = blockIdx.x * 64;
    const int Rw   = R0 + rh * 32;

    // Stage csqr to LDS (covered by the barrier below).
    ((float4*)LsC)[t] = ((const float4*)csqr)[t];

    // ---- A fragments: (-2x) split hi/lo; xsq accumulated (ch==0 waves
    // contribute so each block element is counted exactly once).
    // A layout: lane holds A[m=lane&15][k=quad*8+j], j=0..7.
    f16x8 Ah[2][2], Al[2][2];
    float xsq = 0.0f;
#pragma unroll
    for (int mt = 0; mt < 2; ++mt) {
        const float* xr = X + (size_t)(Rw + mt * 16 + lrow) * D;
#pragma unroll
        for (int ks = 0; ks < 2; ++ks) {
            const int k0 = ks * 32 + quad * 8;
            float4 v0 = *(const float4*)(xr + k0);
            float4 v1 = *(const float4*)(xr + k0 + 4);
            float xs[8] = {v0.x, v0.y, v0.z, v0.w, v1.x, v1.y, v1.z, v1.w};
            f16x8 h, l;
#pragma unroll
            for (int j = 0; j < 8; ++j) {
                xsq += xs[j] * xs[j];
                float sv = -2.0f * xs[j];
                _Float16 hh = (_Float16)sv;
                h[j] = hh;
                l[j] = (_Float16)(sv - (float)hh);
            }
            Ah[mt][ks] = h;
            Al[mt][ks] = l;
        }
    }
    __syncthreads();   // LsC ready

    float bestd[2][4];
    int   besti[2][4];
#pragma unroll
    for (int mt = 0; mt < 2; ++mt)
#pragma unroll
        for (int r = 0; r < 4; ++r) { bestd[mt][r] = 3.0e38f; besti[mt][r] = 0; }

    // Wave's code range starts at tile ch*32.
    const f16x8* gw = (const f16x8*)CBf + (size_t)ch * 32 * 256 + lane;

#define LOADB(Bv, tl)                                                         \
    do {                                                                      \
        const f16x8* _p = gw + (tl) * 256;                                    \
        Bv[0] = _p[0]; Bv[1] = _p[64]; Bv[2] = _p[128]; Bv[3] = _p[192];      \
        __builtin_amdgcn_sched_barrier(0); /* pin: loads may not sink */      \
    } while (0)

#define COMPUTE(Bv, tl)                                                       \
    do {                                                                      \
        const int   c  = (ch * 32 + (tl)) * 16 + lrow;                        \
        const float cs = LsC[c];                                              \
        _Pragma("unroll")                                                     \
        for (int mt = 0; mt < 2; ++mt) {                                      \
            f32x4 acc = {cs, cs, cs, cs};                                     \
            acc = MFMA16(Ah[mt][0], Bv[0], acc);                              \
            acc = MFMA16(Ah[mt][1], Bv[1], acc);                              \
            acc = MFMA16(Al[mt][0], Bv[0], acc);                              \
            acc = MFMA16(Al[mt][1], Bv[1], acc);                              \
            acc = MFMA16(Ah[mt][0], Bv[2], acc);                              \
            acc = MFMA16(Ah[mt][1], Bv[3], acc);                              \
            _Pragma("unroll")                                                 \
            for (int r = 0; r < 4; ++r) {                                     \
                bool lt = acc[r] < bestd[mt][r];                              \
                bestd[mt][r] = lt ? acc[r] : bestd[mt][r];                    \
                besti[mt][r] = lt ? c : besti[mt][r];                         \
            }                                                                 \
        }                                                                     \
    } while (0)

    // 32 local tiles, 4-buffer register pipeline, distance-3 prefetch with
    // pinned load order. Overrun prefetches wrap via &31 (tiles reloaded
    // but never computed) so every load stays inside CBf. Codes ascend with
    // tl for fixed lane -> strict < keeps first minimum (np.argmin).
    f16x8 B0[4], B1[4], B2[4], B3[4];
    LOADB(B0, 0);
    LOADB(B1, 1);
    LOADB(B2, 2);
    for (int tl = 0; tl < 32; tl += 4) {
        LOADB(B3, (tl + 3) & 31);
        COMPUTE(B0, tl);
        LOADB(B0, (tl + 4) & 31);
        COMPUTE(B1, tl + 1);
        LOADB(B1, (tl + 5) & 31);
        COMPUTE(B2, tl + 2);
        LOADB(B2, (tl + 6) & 31);
        COMPUTE(B3, tl + 3);
    }

    // ---- xsq: reduce within ch==0 waves (each block element once).
    if (ch == 0) {
        float s = xsq;
#pragma unroll
        for (int m = 1; m < 64; m <<= 1) s += __shfl_xor(s, m, 64);
        if (lane == 0) xsqW[rh] = s;
    }

    // ---- In-wave argmin reduce across the 16 code-columns (lexicographic
    // on exact ties), deposit per-row candidate for this code half.
#pragma unroll
    for (int mt = 0; mt < 2; ++mt) {
#pragma unroll
        for (int r = 0; r < 4; ++r) {
            float dv = bestd[mt][r];
            int   iv = besti[mt][r];
#pragma unroll
            for (int m = 1; m < 16; m <<= 1) {
                float od = __shfl_xor(dv, m, 64);
                int   oi = __shfl_xor(iv, m, 64);
                if (od < dv || (od == dv && oi < iv)) { dv = od; iv = oi; }
            }
            if (lrow == 0) {
                int rl = rh * 32 + mt * 16 + quad * 4 + r;   // 0..63
                candD[rl][ch] = dv;
                candI[rl][ch] = iv;
            }
        }
    }
    __syncthreads();

    // ---- Merge the two code halves; write idxf; accumulate loss.
    const float scale = 1.25f / (float)((size_t)N_ROWS * D);
    if (t < 64) {
        float d0 = candD[t][0], d1 = candD[t][1];
        int   i0 = candI[t][0], i1 = candI[t][1];
        // ch0 indices are all < ch1 indices -> tie keeps ch0 (first min).
        bool take1 = d1 < d0;
        float dv = take1 ? d1 : d0;
        int   iv = take1 ? i1 : i0;
        out[1 + (size_t)N_ROWS * D + R0 + t] = (float)iv;   // idxf
        ivfin[t] = iv;
        float ssum = dv;
#pragma unroll
        for (int m = 1; m < 64; m <<= 1) ssum += __shfl_xor(ssum, m, 64);
        if (t == 0)
            atomicAdd(out, (ssum + xsqW[0] + xsqW[1]) * scale);
    }
    __syncthreads();

    // ---- Block-cooperative zq span write: dwords [R0*64, R0*64+4096) at
    // out+1. Global dword offset 1+R0*64+j is 16B-aligned iff j%4==3.
    float* p = out + 1 + (size_t)R0 * D;
#pragma unroll
    for (int i = 0; i < 4; ++i) {
        int q = i * 256 + t;        // 0..1023
        int j = 4 * q + 3;          // 3,7,...,4095
        if (q < 1023) {
            float v[4];
#pragma unroll
            for (int e = 0; e < 4; ++e) {
                int jj = j + e;     // may straddle a row boundary
                v[e] = CB[(size_t)ivfin[jj >> 6] * D + (jj & 63)];
            }
            *(float4*)(p + j) = make_float4(v[0], v[1], v[2], v[3]);
        } else if (q == 1023) {
            p[4095] = CB[(size_t)ivfin[63] * D + 63];
        }
    }
    if (t == 0) {   // head dwords j=0..2 (row 0, cols 0..2)
        const float* c0 = CB + (size_t)ivfin[0] * D;
        p[0] = c0[0];
        p[1] = c0[1];
        p[2] = c0[2];
    }
}

// ---------------------------------------------------------------------------
extern "C" void kernel_launch(void* const* d_in, const int* in_sizes, int n_in,
                              void* d_out, int out_size, void* d_ws,
                              size_t ws_size, hipStream_t stream) {
    const float* X  = (const float*)d_in[0];   // inputs  [131072,64]
    const float* CB = (const float*)d_in[1];   // codebook [1024,64]

    float*    csqr = (float*)d_ws;                      // 4 KB
    _Float16* CBf  = (_Float16*)((char*)d_ws + 4096);   // 256 KB

    hipLaunchKernelGGL(prep_kernel, dim3(65), dim3(256), 0, stream,
                       CB, CBf, csqr, (float*)d_out);
    hipLaunchKernelGGL(argmin_kernel, dim3(N_ROWS / 64), dim3(256), 0, stream,
                       X, CBf, csqr, CB, (float*)d_out);
}